// Round 8
// baseline (344.949 us; speedup 1.0000x reference)
//
#include <hip/hip_runtime.h>
#include <hip/hip_bf16.h>

// Problem constants (fixed by the reference file)
#define BB   32      // batch
#define TT   512     // time
#define II   128     // input dim
#define HH   128     // hidden per rnn
#define NR   16      // num independent rnn blocks
#define HTOT 2048    // HH * NR

typedef __attribute__((ext_vector_type(8))) short short8;   // 8 bf16 (4 VGPR) MFMA A/B frag
typedef __attribute__((ext_vector_type(4))) float f32x4;    // MFMA C/D frag

static __device__ __forceinline__ short f2bf(float f) {
    union { __hip_bfloat16 h; short s; } u;
    u.h = __float2bfloat16(f);
    return u.s;
}
static __device__ __forceinline__ float bf2f(unsigned short u) {
    return __uint_as_float(((unsigned int)u) << 16);
}

// ---------------------------------------------------------------------------
// Kernel 1 (unchanged, known good):
// pre = x @ W_ih^T + b_ih + b_hh, bf16 to ws, layout pre[(n*2+g)][t][m][j].
// ---------------------------------------------------------------------------
__global__ __launch_bounds__(512, 2) void msml_pre(
    const float* __restrict__ x,     // (B,T,I)
    const float* __restrict__ Wih,   // (HTOT, II)
    const float* __restrict__ bih,
    const float* __restrict__ bhh,
    unsigned short* __restrict__ pre)
{
    const int mx = blockIdx.x;      // 0..127
    const int n  = blockIdx.y;      // 0..15
    const int tid = threadIdx.x;
    const int w = tid >> 6, l = tid & 63;
    const int q = l >> 4;
    const int r0 = mx * 128;
    const int b  = r0 >> 9;
    const int t0 = r0 & 511;
    const int g  = b >> 4, m = b & 15;

    __shared__ short A[128 * 136];

    {
        const int row = tid >> 2, cb = tid & 3;
        const float4* xs = reinterpret_cast<const float4*>(x + (size_t)(r0 + row) * II + cb * 32);
        short* dst = &A[row * 136 + cb * 32];
#pragma unroll
        for (int i = 0; i < 8; ++i) {
            float4 v = xs[i];
            *reinterpret_cast<short4*>(dst + 4 * i) =
                make_short4(f2bf(v.x), f2bf(v.y), f2bf(v.z), f2bf(v.w));
        }
    }

    const int j = w * 16 + (l & 15);
    short8 bw[4];
    {
        const float* wb = Wih + (size_t)(n * HH + j) * II + q * 8;
#pragma unroll
        for (int kt = 0; kt < 4; ++kt) {
            float4 u0 = *reinterpret_cast<const float4*>(wb + kt * 32);
            float4 u1 = *reinterpret_cast<const float4*>(wb + kt * 32 + 4);
            short8 s;
            s[0] = f2bf(u0.x); s[1] = f2bf(u0.y); s[2] = f2bf(u0.z); s[3] = f2bf(u0.w);
            s[4] = f2bf(u1.x); s[5] = f2bf(u1.y); s[6] = f2bf(u1.z); s[7] = f2bf(u1.w);
            bw[kt] = s;
        }
    }
    const float bias = bih[n * HH + j] + bhh[n * HH + j];
    __syncthreads();

    const size_t ng = (size_t)(n * 2 + g);
#pragma unroll
    for (int mt = 0; mt < 8; ++mt) {
        const short* ap = &A[(mt * 16 + (l & 15)) * 136 + q * 8];
        f32x4 acc = {0.f, 0.f, 0.f, 0.f};
#pragma unroll
        for (int kt = 0; kt < 4; ++kt) {
            short8 a = *reinterpret_cast<const short8*>(ap + kt * 32);
            acc = __builtin_amdgcn_mfma_f32_16x16x32_bf16(a, bw[kt], acc, 0, 0, 0);
        }
#pragma unroll
        for (int r = 0; r < 4; ++r) {
            const int t = t0 + mt * 16 + q * 4 + r;
            pre[((ng * TT + t) * 16 + m) * 128 + j] = (unsigned short)f2bf(acc[r] + bias);
        }
    }
}

// ---------------------------------------------------------------------------
// Kernel 2: 4-wave recurrence, A-stationary (r5 operand order, verified).
// One WG per (n, batch-group g): 32 WGs x 4 waves (256 thr). Wave w owns
// j in [32w, 32w+32) as 2 MFMA n-tiles; A = Wn rows in regs (2x4 frags),
// B = H^T from LDS -- the 4 ds_read_b128 of H are SHARED by both tiles, so
// LDS read traffic halves vs the 8-wave version and writes become packed
// b64 (bank-balanced). C of chain0 is seeded with pre[t] (no VALU add).
// pre prefetched 3 steps ahead (covers HBM miss + in-order store retire).
// Barrier = verified r7 idiom (lgkmcnt-only, no vmcnt drain).
// ---------------------------------------------------------------------------
__global__ __launch_bounds__(256, 1) void msml_recur4w(
    const float* __restrict__ Whh,            // (HTOT, HTOT)
    const unsigned short* __restrict__ pre,   // bf16 (NR*2, TT, 16, 128)
    float* __restrict__ out)
{
    const int n = blockIdx.x;   // 0..15
    const int g = blockIdx.y;   // 0..1
    const int tid = threadIdx.x;
    const int w = tid >> 6;     // wave 0..3
    const int l = tid & 63;
    const int m = l & 15;       // batch (B col / D col)
    const int q = l >> 4;       // 0..3

    __shared__ short Hs[2][16 * 136];   // H[batch][j] bf16, row stride 136

    // ---- stationary A-frags: wf[jt][kt] = Wn[(2w+jt)*16 + m][kt*32+q*8..+7] ----
    short8 wf[2][4];
#pragma unroll
    for (int jt = 0; jt < 2; ++jt)
#pragma unroll
        for (int kt = 0; kt < 4; ++kt) {
            const float* wp = Whh + (size_t)(n * HH + (2 * w + jt) * 16 + m) * HTOT
                              + n * HH + kt * 32 + q * 8;
            float4 u0 = *reinterpret_cast<const float4*>(wp);
            float4 u1 = *reinterpret_cast<const float4*>(wp + 4);
            short8 s;
            s[0] = f2bf(u0.x); s[1] = f2bf(u0.y); s[2] = f2bf(u0.z); s[3] = f2bf(u0.w);
            s[4] = f2bf(u1.x); s[5] = f2bf(u1.y); s[6] = f2bf(u1.z); s[7] = f2bf(u1.w);
            wf[jt][kt] = s;
        }

    const short8 zs = {0, 0, 0, 0, 0, 0, 0, 0};
    const f32x4 zero4 = {0.f, 0.f, 0.f, 0.f};

    // pre address: batch m, cols (2w+jt)*16 + q*4 .. +3 (ushort4); jt offset +16
    const unsigned short* pb = pre + (size_t)(n * 2 + g) * TT * 2048 + m * 128
                               + 2 * w * 16 + q * 4;
    // output base: row b = g*16+m, col n*128 + 2w*16 + q*4
    float* ob = out + (size_t)(g * 16 + m) * TT * HTOT + n * HH + 2 * w * 16 + q * 4;

    // ---- 3-deep pre prefetch; h_{-1} = 0 in registers (no LDS zeroing) ----
    ushort4 pA0 = *reinterpret_cast<const ushort4*>(pb);
    ushort4 pA1 = *reinterpret_cast<const ushort4*>(pb + 16);
    ushort4 pB0 = *reinterpret_cast<const ushort4*>(pb + 2048);
    ushort4 pB1 = *reinterpret_cast<const ushort4*>(pb + 2048 + 16);
    ushort4 pC0 = *reinterpret_cast<const ushort4*>(pb + 2 * 2048);
    ushort4 pC1 = *reinterpret_cast<const ushort4*>(pb + 2 * 2048 + 16);

    short8 hf[4];
#pragma unroll
    for (int kt = 0; kt < 4; ++kt) hf[kt] = zs;

    for (int t = 0; t < TT; ++t) {
        const bool last = (t == TT - 1);

        // ---- issue pre load for t+3 (3 loads in flight per tile) ----
        const int tn = (t + 3 < TT) ? t + 3 : TT - 1;
        ushort4 pD0 = *reinterpret_cast<const ushort4*>(pb + (size_t)tn * 2048);
        ushort4 pD1 = *reinterpret_cast<const ushort4*>(pb + (size_t)tn * 2048 + 16);

        // ---- 4 independent depth-2 MFMA chains (2 per j-tile) ----
        f32x4 c0, c1;
        c0[0] = bf2f(pA0.x); c0[1] = bf2f(pA0.y); c0[2] = bf2f(pA0.z); c0[3] = bf2f(pA0.w);
        c1[0] = bf2f(pA1.x); c1[1] = bf2f(pA1.y); c1[2] = bf2f(pA1.z); c1[3] = bf2f(pA1.w);
        f32x4 a00 = __builtin_amdgcn_mfma_f32_16x16x32_bf16(wf[0][0], hf[0], c0, 0, 0, 0);
        f32x4 a10 = __builtin_amdgcn_mfma_f32_16x16x32_bf16(wf[1][0], hf[0], c1, 0, 0, 0);
        f32x4 a01 = __builtin_amdgcn_mfma_f32_16x16x32_bf16(wf[0][2], hf[2], zero4, 0, 0, 0);
        f32x4 a11 = __builtin_amdgcn_mfma_f32_16x16x32_bf16(wf[1][2], hf[2], zero4, 0, 0, 0);
        a00 = __builtin_amdgcn_mfma_f32_16x16x32_bf16(wf[0][1], hf[1], a00, 0, 0, 0);
        a10 = __builtin_amdgcn_mfma_f32_16x16x32_bf16(wf[1][1], hf[1], a10, 0, 0, 0);
        a01 = __builtin_amdgcn_mfma_f32_16x16x32_bf16(wf[0][3], hf[3], a01, 0, 0, 0);
        a11 = __builtin_amdgcn_mfma_f32_16x16x32_bf16(wf[1][3], hf[3], a11, 0, 0, 0);

        // ---- epilogue per tile: relu, pack bf16 -> LDS b64, fp32x4 -> out ----
        float h00 = fmaxf(a00[0] + a01[0], 0.f);
        float h01 = fmaxf(a00[1] + a01[1], 0.f);
        float h02 = fmaxf(a00[2] + a01[2], 0.f);
        float h03 = fmaxf(a00[3] + a01[3], 0.f);
        float h10 = fmaxf(a10[0] + a11[0], 0.f);
        float h11 = fmaxf(a10[1] + a11[1], 0.f);
        float h12 = fmaxf(a10[2] + a11[2], 0.f);
        float h13 = fmaxf(a10[3] + a11[3], 0.f);

        short* hw = &Hs[t & 1][m * 136 + 2 * w * 16 + q * 4];
        {
            unsigned int u0 = (unsigned int)(unsigned short)f2bf(h00) |
                              ((unsigned int)(unsigned short)f2bf(h01) << 16);
            unsigned int u1 = (unsigned int)(unsigned short)f2bf(h02) |
                              ((unsigned int)(unsigned short)f2bf(h03) << 16);
            *reinterpret_cast<uint2*>(hw) = make_uint2(u0, u1);
            unsigned int u2 = (unsigned int)(unsigned short)f2bf(h10) |
                              ((unsigned int)(unsigned short)f2bf(h11) << 16);
            unsigned int u3 = (unsigned int)(unsigned short)f2bf(h12) |
                              ((unsigned int)(unsigned short)f2bf(h13) << 16);
            *reinterpret_cast<uint2*>(hw + 16) = make_uint2(u2, u3);
        }

        float* oo = ob + (size_t)t * HTOT;
        *reinterpret_cast<float4*>(oo)      = make_float4(h00, h01, h02, h03);
        *reinterpret_cast<float4*>(oo + 16) = make_float4(h10, h11, h12, h13);

        if (last) {
            float* hh = out + (size_t)BB * TT * HTOT + (size_t)(g * 16 + m) * HTOT
                        + n * HH + 2 * w * 16 + q * 4;
            *reinterpret_cast<float4*>(hh)      = make_float4(h00, h01, h02, h03);
            *reinterpret_cast<float4*>(hh + 16) = make_float4(h10, h11, h12, h13);
            break;
        }

        // ---- LDS-only barrier (r7-verified idiom, no vmcnt drain) ----
        __builtin_amdgcn_sched_barrier(0);
        asm volatile("s_waitcnt lgkmcnt(0)");
        __builtin_amdgcn_s_barrier();
        __builtin_amdgcn_sched_barrier(0);

        // ---- read H_t (shared by both tiles next step) ----
        const short* hr = &Hs[t & 1][m * 136 + q * 8];
#pragma unroll
        for (int kt = 0; kt < 4; ++kt)
            hf[kt] = *reinterpret_cast<const short8*>(hr + kt * 32);

        pA0 = pB0; pA1 = pB1; pB0 = pC0; pB1 = pC1; pC0 = pD0; pC1 = pD1;
    }
}

// ---------------------------------------------------------------------------
// Fallback (round-2 kernel, known-good): used if ws_size is too small.
// ---------------------------------------------------------------------------
__global__ __launch_bounds__(512, 4) void msml_fused2(
    const float* __restrict__ x,
    const float* __restrict__ Wih,
    const float* __restrict__ Whh,
    const float* __restrict__ bih,
    const float* __restrict__ bhh,
    float* __restrict__ out)
{
    const int n    = blockIdx.x;
    const int b    = blockIdx.y;
    const int tid  = threadIdx.x;
    const int wave = tid >> 6;
    const int lane = tid & 63;
    const int s    = lane >> 4;
    const int j    = wave * 16 + (lane & 15);
    const int row  = n * HH + j;

    float wih[32], whh[32];
    {
        const float4* wi4 = reinterpret_cast<const float4*>(Wih + (size_t)row * II);
        const float4* wh4 = reinterpret_cast<const float4*>(Whh + (size_t)row * HTOT + n * HH);
#pragma unroll
        for (int k = 0; k < 8; ++k) {
            float4 a = wi4[4 * k + s];
            wih[4*k+0] = a.x; wih[4*k+1] = a.y; wih[4*k+2] = a.z; wih[4*k+3] = a.w;
            float4 c = wh4[4 * k + s];
            whh[4*k+0] = c.x; whh[4*k+1] = c.y; whh[4*k+2] = c.z; whh[4*k+3] = c.w;
        }
    }
    const float bias0 = (s == 0) ? (bih[row] + bhh[row]) : 0.0f;

    __shared__ float hs[2][HH];
    if (tid < HH) hs[0][tid] = 0.0f;

    const float* xrow = x + (size_t)b * TT * II;
    float* orow = out + (size_t)b * TT * HTOT + (size_t)n * HH + j;

    float accx;
    {
        const float4* xv = reinterpret_cast<const float4*>(xrow);
        float a0 = bias0, a1 = 0.f, a2 = 0.f, a3 = 0.f;
#pragma unroll
        for (int k = 0; k < 8; ++k) {
            float4 v = xv[4 * k + s];
            a0 += wih[4*k+0] * v.x; a1 += wih[4*k+1] * v.y;
            a2 += wih[4*k+2] * v.z; a3 += wih[4*k+3] * v.w;
        }
        accx = (a0 + a1) + (a2 + a3);
    }
    __syncthreads();

    float hn = 0.0f;
    int buf = 0;
    for (int t = 0; t < TT; ++t) {
        float4 xn[8];
        if (t + 1 < TT) {
            const float4* xv = reinterpret_cast<const float4*>(xrow + (size_t)(t + 1) * II);
#pragma unroll
            for (int k = 0; k < 8; ++k) xn[k] = xv[4 * k + s];
        }
        const float4* hv = reinterpret_cast<const float4*>(hs[buf]);
        float a0 = accx, a1 = 0.f, a2 = 0.f, a3 = 0.f;
#pragma unroll
        for (int k = 0; k < 8; ++k) {
            float4 v = hv[4 * k + s];
            a0 += whh[4*k+0] * v.x; a1 += whh[4*k+1] * v.y;
            a2 += whh[4*k+2] * v.z; a3 += whh[4*k+3] * v.w;
        }
        float sum = (a0 + a1) + (a2 + a3);
        sum += __shfl_xor(sum, 16);
        sum += __shfl_xor(sum, 32);
        hn = fmaxf(sum, 0.0f);

        if (s == 0) {
            orow[(size_t)t * HTOT] = hn;
            hs[buf ^ 1][j] = hn;
        }
        {
            float b0 = bias0, b1 = 0.f, b2 = 0.f, b3 = 0.f;
#pragma unroll
            for (int k = 0; k < 8; ++k) {
                b0 += wih[4*k+0] * xn[k].x; b1 += wih[4*k+1] * xn[k].y;
                b2 += wih[4*k+2] * xn[k].z; b3 += wih[4*k+3] * xn[k].w;
            }
            accx = (b0 + b1) + (b2 + b3);
        }
        buf ^= 1;
        __syncthreads();
    }

    if (s == 0)
        out[(size_t)BB * TT * HTOT + (size_t)b * HTOT + row] = hn;
}

extern "C" void kernel_launch(void* const* d_in, const int* in_sizes, int n_in,
                              void* d_out, int out_size, void* d_ws, size_t ws_size,
                              hipStream_t stream) {
    const float* x   = (const float*)d_in[0];
    const float* Wih = (const float*)d_in[1];
    const float* Whh = (const float*)d_in[2];
    const float* bih = (const float*)d_in[3];
    const float* bhh = (const float*)d_in[4];
    float* out = (float*)d_out;

    const size_t pre_bytes = (size_t)NR * 2 * TT * 16 * 128 * sizeof(unsigned short); // 64 MiB

    if (ws_size >= pre_bytes && d_ws != nullptr) {
        unsigned short* pre = (unsigned short*)d_ws;
        msml_pre<<<dim3(128, NR), 512, 0, stream>>>(x, Wih, bih, bhh, pre);
        msml_recur4w<<<dim3(NR, 2), 256, 0, stream>>>(Whh, pre, out);
    } else {
        msml_fused2<<<dim3(NR, BB), 512, 0, stream>>>(x, Wih, Whh, bih, bhh, out);
    }
}

// Round 9
// 266.712 us; speedup vs baseline: 1.2933x; 1.2933x over previous
//
#include <hip/hip_runtime.h>
#include <hip/hip_bf16.h>

// Problem constants (fixed by the reference file)
#define BB   32      // batch
#define TT   512     // time
#define II   128     // input dim
#define HH   128     // hidden per rnn
#define NR   16      // num independent rnn blocks
#define HTOT 2048    // HH * NR

typedef __attribute__((ext_vector_type(8))) short short8;   // 8 bf16 (4 VGPR) MFMA A/B frag
typedef __attribute__((ext_vector_type(4))) float f32x4;    // MFMA C/D frag

static __device__ __forceinline__ short f2bf(float f) {
    union { __hip_bfloat16 h; short s; } u;
    u.h = __float2bfloat16(f);
    return u.s;
}
static __device__ __forceinline__ float bf2f(unsigned short u) {
    return __uint_as_float(((unsigned int)u) << 16);
}

// ---------------------------------------------------------------------------
// Kernel 1 (unchanged, known good):
// pre = x @ W_ih^T + b_ih + b_hh, bf16 to ws, layout pre[(n*2+g)][t][m][j].
// ---------------------------------------------------------------------------
__global__ __launch_bounds__(512, 2) void msml_pre(
    const float* __restrict__ x,     // (B,T,I)
    const float* __restrict__ Wih,   // (HTOT, II)
    const float* __restrict__ bih,
    const float* __restrict__ bhh,
    unsigned short* __restrict__ pre)
{
    const int mx = blockIdx.x;      // 0..127
    const int n  = blockIdx.y;      // 0..15
    const int tid = threadIdx.x;
    const int w = tid >> 6, l = tid & 63;
    const int q = l >> 4;
    const int r0 = mx * 128;
    const int b  = r0 >> 9;
    const int t0 = r0 & 511;
    const int g  = b >> 4, m = b & 15;

    __shared__ short A[128 * 136];

    {
        const int row = tid >> 2, cb = tid & 3;
        const float4* xs = reinterpret_cast<const float4*>(x + (size_t)(r0 + row) * II + cb * 32);
        short* dst = &A[row * 136 + cb * 32];
#pragma unroll
        for (int i = 0; i < 8; ++i) {
            float4 v = xs[i];
            *reinterpret_cast<short4*>(dst + 4 * i) =
                make_short4(f2bf(v.x), f2bf(v.y), f2bf(v.z), f2bf(v.w));
        }
    }

    const int j = w * 16 + (l & 15);
    short8 bw[4];
    {
        const float* wb = Wih + (size_t)(n * HH + j) * II + q * 8;
#pragma unroll
        for (int kt = 0; kt < 4; ++kt) {
            float4 u0 = *reinterpret_cast<const float4*>(wb + kt * 32);
            float4 u1 = *reinterpret_cast<const float4*>(wb + kt * 32 + 4);
            short8 s;
            s[0] = f2bf(u0.x); s[1] = f2bf(u0.y); s[2] = f2bf(u0.z); s[3] = f2bf(u0.w);
            s[4] = f2bf(u1.x); s[5] = f2bf(u1.y); s[6] = f2bf(u1.z); s[7] = f2bf(u1.w);
            bw[kt] = s;
        }
    }
    const float bias = bih[n * HH + j] + bhh[n * HH + j];
    __syncthreads();

    const size_t ng = (size_t)(n * 2 + g);
#pragma unroll
    for (int mt = 0; mt < 8; ++mt) {
        const short* ap = &A[(mt * 16 + (l & 15)) * 136 + q * 8];
        f32x4 acc = {0.f, 0.f, 0.f, 0.f};
#pragma unroll
        for (int kt = 0; kt < 4; ++kt) {
            short8 a = *reinterpret_cast<const short8*>(ap + kt * 32);
            acc = __builtin_amdgcn_mfma_f32_16x16x32_bf16(a, bw[kt], acc, 0, 0, 0);
        }
#pragma unroll
        for (int r = 0; r < 4; ++r) {
            const int t = t0 + mt * 16 + q * 4 + r;
            pre[((ng * TT + t) * 16 + m) * 128 + j] = (unsigned short)f2bf(acc[r] + bias);
        }
    }
}

// ---------------------------------------------------------------------------
// Kernel 2: 8-wave A-stationary recurrence (r5 operand mapping, verified) +
// r7 barrier idiom (lgkmcnt-only, verified) + 3-deep pre prefetch + XOR-
// swizzled LDS. One WG per (n, batch-group g): 32 WGs x 8 waves.
// Wave w owns j-tile [16w,16w+16); A = Wn rows in regs (4 frags), B = H^T
// from LDS (4x ds_read_b128/wave, the per-wave floor), D cols = batch ->
// each lane writes its 4 outputs as ONE packed b64 (8 write instrs/WG/step
// vs 32 scalar in r7, and no column-scatter conflicts).
// LDS layout: H[m][k] bf16, row = 16 blocks of 16B, block' = block ^ m.
// Uniform bank load for reads (8/bank) and writes (4/bank) = conflict-free.
// ---------------------------------------------------------------------------
__global__ __launch_bounds__(512, 2) void msml_recur8wA(
    const float* __restrict__ Whh,            // (HTOT, HTOT)
    const unsigned short* __restrict__ pre,   // bf16 (NR*2, TT, 16, 128)
    float* __restrict__ out)
{
    const int n = blockIdx.x;   // 0..15
    const int g = blockIdx.y;   // 0..1
    const int tid = threadIdx.x;
    const int w = tid >> 6;     // wave = j-tile
    const int l = tid & 63;
    const int m = l & 15;       // batch (B col / D col); also A row-within-tile
    const int q = l >> 4;       // 0..3

    __shared__ short Hs[2][16 * 128];   // swizzled, no pad

    // ---- stationary A-frags: wf[kt] = Wn[w*16 + m][kt*32 + q*8 .. +7] ----
    short8 wf[4];
#pragma unroll
    for (int kt = 0; kt < 4; ++kt) {
        const float* wp = Whh + (size_t)(n * HH + w * 16 + m) * HTOT + n * HH + kt * 32 + q * 8;
        float4 u0 = *reinterpret_cast<const float4*>(wp);
        float4 u1 = *reinterpret_cast<const float4*>(wp + 4);
        short8 s;
        s[0] = f2bf(u0.x); s[1] = f2bf(u0.y); s[2] = f2bf(u0.z); s[3] = f2bf(u0.w);
        s[4] = f2bf(u1.x); s[5] = f2bf(u1.y); s[6] = f2bf(u1.z); s[7] = f2bf(u1.w);
        wf[kt] = s;
    }

    const short8 zs = {0, 0, 0, 0, 0, 0, 0, 0};
    const f32x4 zero4 = {0.f, 0.f, 0.f, 0.f};

    // swizzled LDS offsets (shorts)
    //   write: H[m][j0 = w*16+q*4 .. +3]: block = w*2+(q>>1), half = (q&1)*4
    const int wr_off = m * 128 + (((w * 2 + (q >> 1)) ^ m) * 8) + (q & 1) * 4;
    //   read kt: H[m][kt*32+q*8 .. +7]: block = kt*4+q
    int rd_off[4];
#pragma unroll
    for (int kt = 0; kt < 4; ++kt) rd_off[kt] = m * 128 + (((kt * 4 + q) ^ m) * 8);

    // per-lane pre address: batch m, cols w*16 + q*4 .. +3 (ushort4)
    const unsigned short* pb = pre + (size_t)(n * 2 + g) * TT * 2048 + m * 128 + w * 16 + q * 4;
    // output base: row b = g*16+m, col n*128 + w*16 + q*4
    float* ob = out + (size_t)(g * 16 + m) * TT * HTOT + n * HH + w * 16 + q * 4;

    // ---- 3-deep pre prefetch; h_{-1} = 0 in registers ----
    ushort4 pA = *reinterpret_cast<const ushort4*>(pb);
    ushort4 pB = *reinterpret_cast<const ushort4*>(pb + 2048);
    ushort4 pC = *reinterpret_cast<const ushort4*>(pb + 2 * 2048);
    short8 hf[4];
#pragma unroll
    for (int kt = 0; kt < 4; ++kt) hf[kt] = zs;

    for (int t = 0; t < TT; ++t) {
        const bool last = (t == TT - 1);

        // ---- issue pre load for t+3 (3 loads in flight) ----
        const int tn = (t + 3 < TT) ? t + 3 : TT - 1;
        ushort4 pD = *reinterpret_cast<const ushort4*>(pb + (size_t)tn * 2048);

        // ---- two depth-2 MFMA chains; chain0 seeded with pre[t] ----
        f32x4 c0;
        c0[0] = bf2f(pA.x); c0[1] = bf2f(pA.y);
        c0[2] = bf2f(pA.z); c0[3] = bf2f(pA.w);
        f32x4 a0 = __builtin_amdgcn_mfma_f32_16x16x32_bf16(wf[0], hf[0], c0, 0, 0, 0);
        f32x4 a1 = __builtin_amdgcn_mfma_f32_16x16x32_bf16(wf[2], hf[2], zero4, 0, 0, 0);
        a0 = __builtin_amdgcn_mfma_f32_16x16x32_bf16(wf[1], hf[1], a0, 0, 0, 0);
        a1 = __builtin_amdgcn_mfma_f32_16x16x32_bf16(wf[3], hf[3], a1, 0, 0, 0);

        // ---- epilogue: relu, pack bf16 -> ONE b64 LDS write ----
        float h0 = fmaxf(a0[0] + a1[0], 0.f);
        float h1 = fmaxf(a0[1] + a1[1], 0.f);
        float h2 = fmaxf(a0[2] + a1[2], 0.f);
        float h3 = fmaxf(a0[3] + a1[3], 0.f);

        unsigned int u0 = (unsigned int)(unsigned short)f2bf(h0) |
                          ((unsigned int)(unsigned short)f2bf(h1) << 16);
        unsigned int u1 = (unsigned int)(unsigned short)f2bf(h2) |
                          ((unsigned int)(unsigned short)f2bf(h3) << 16);
        *reinterpret_cast<uint2*>(&Hs[t & 1][wr_off]) = make_uint2(u0, u1);

        // ---- global store (fire-and-forget, floats across barrier) ----
        *reinterpret_cast<float4*>(ob + (size_t)t * HTOT) = make_float4(h0, h1, h2, h3);

        if (last) {
            *reinterpret_cast<float4*>(out + (size_t)BB * TT * HTOT +
                                       (size_t)(g * 16 + m) * HTOT + n * HH + w * 16 + q * 4) =
                make_float4(h0, h1, h2, h3);
            break;
        }

        // ---- LDS-only barrier (r7-verified idiom, no vmcnt drain) ----
        __builtin_amdgcn_sched_barrier(0);
        asm volatile("s_waitcnt lgkmcnt(0)");
        __builtin_amdgcn_s_barrier();
        __builtin_amdgcn_sched_barrier(0);

        // ---- read full H_t as B-frags for next step ----
        {
            const short* hb = &Hs[t & 1][0];
#pragma unroll
            for (int kt = 0; kt < 4; ++kt)
                hf[kt] = *reinterpret_cast<const short8*>(hb + rd_off[kt]);
        }

        pA = pB; pB = pC; pC = pD;
    }
}

// ---------------------------------------------------------------------------
// Fallback (round-2 kernel, known-good): used if ws_size is too small.
// ---------------------------------------------------------------------------
__global__ __launch_bounds__(512, 4) void msml_fused2(
    const float* __restrict__ x,
    const float* __restrict__ Wih,
    const float* __restrict__ Whh,
    const float* __restrict__ bih,
    const float* __restrict__ bhh,
    float* __restrict__ out)
{
    const int n    = blockIdx.x;
    const int b    = blockIdx.y;
    const int tid  = threadIdx.x;
    const int wave = tid >> 6;
    const int lane = tid & 63;
    const int s    = lane >> 4;
    const int j    = wave * 16 + (lane & 15);
    const int row  = n * HH + j;

    float wih[32], whh[32];
    {
        const float4* wi4 = reinterpret_cast<const float4*>(Wih + (size_t)row * II);
        const float4* wh4 = reinterpret_cast<const float4*>(Whh + (size_t)row * HTOT + n * HH);
#pragma unroll
        for (int k = 0; k < 8; ++k) {
            float4 a = wi4[4 * k + s];
            wih[4*k+0] = a.x; wih[4*k+1] = a.y; wih[4*k+2] = a.z; wih[4*k+3] = a.w;
            float4 c = wh4[4 * k + s];
            whh[4*k+0] = c.x; whh[4*k+1] = c.y; whh[4*k+2] = c.z; whh[4*k+3] = c.w;
        }
    }
    const float bias0 = (s == 0) ? (bih[row] + bhh[row]) : 0.0f;

    __shared__ float hs[2][HH];
    if (tid < HH) hs[0][tid] = 0.0f;

    const float* xrow = x + (size_t)b * TT * II;
    float* orow = out + (size_t)b * TT * HTOT + (size_t)n * HH + j;

    float accx;
    {
        const float4* xv = reinterpret_cast<const float4*>(xrow);
        float a0 = bias0, a1 = 0.f, a2 = 0.f, a3 = 0.f;
#pragma unroll
        for (int k = 0; k < 8; ++k) {
            float4 v = xv[4 * k + s];
            a0 += wih[4*k+0] * v.x; a1 += wih[4*k+1] * v.y;
            a2 += wih[4*k+2] * v.z; a3 += wih[4*k+3] * v.w;
        }
        accx = (a0 + a1) + (a2 + a3);
    }
    __syncthreads();

    float hn = 0.0f;
    int buf = 0;
    for (int t = 0; t < TT; ++t) {
        float4 xn[8];
        if (t + 1 < TT) {
            const float4* xv = reinterpret_cast<const float4*>(xrow + (size_t)(t + 1) * II);
#pragma unroll
            for (int k = 0; k < 8; ++k) xn[k] = xv[4 * k + s];
        }
        const float4* hv = reinterpret_cast<const float4*>(hs[buf]);
        float a0 = accx, a1 = 0.f, a2 = 0.f, a3 = 0.f;
#pragma unroll
        for (int k = 0; k < 8; ++k) {
            float4 v = hv[4 * k + s];
            a0 += whh[4*k+0] * v.x; a1 += whh[4*k+1] * v.y;
            a2 += whh[4*k+2] * v.z; a3 += whh[4*k+3] * v.w;
        }
        float sum = (a0 + a1) + (a2 + a3);
        sum += __shfl_xor(sum, 16);
        sum += __shfl_xor(sum, 32);
        hn = fmaxf(sum, 0.0f);

        if (s == 0) {
            orow[(size_t)t * HTOT] = hn;
            hs[buf ^ 1][j] = hn;
        }
        {
            float b0 = bias0, b1 = 0.f, b2 = 0.f, b3 = 0.f;
#pragma unroll
            for (int k = 0; k < 8; ++k) {
                b0 += wih[4*k+0] * xn[k].x; b1 += wih[4*k+1] * xn[k].y;
                b2 += wih[4*k+2] * xn[k].z; b3 += wih[4*k+3] * xn[k].w;
            }
            accx = (b0 + b1) + (b2 + b3);
        }
        buf ^= 1;
        __syncthreads();
    }

    if (s == 0)
        out[(size_t)BB * TT * HTOT + (size_t)b * HTOT + row] = hn;
}

extern "C" void kernel_launch(void* const* d_in, const int* in_sizes, int n_in,
                              void* d_out, int out_size, void* d_ws, size_t ws_size,
                              hipStream_t stream) {
    const float* x   = (const float*)d_in[0];
    const float* Wih = (const float*)d_in[1];
    const float* Whh = (const float*)d_in[2];
    const float* bih = (const float*)d_in[3];
    const float* bhh = (const float*)d_in[4];
    float* out = (float*)d_out;

    const size_t pre_bytes = (size_t)NR * 2 * TT * 16 * 128 * sizeof(unsigned short); // 64 MiB

    if (ws_size >= pre_bytes && d_ws != nullptr) {
        unsigned short* pre = (unsigned short*)d_ws;
        msml_pre<<<dim3(128, NR), 512, 0, stream>>>(x, Wih, bih, bhh, pre);
        msml_recur8wA<<<dim3(NR, 2), 512, 0, stream>>>(Whh, pre, out);
    } else {
        msml_fused2<<<dim3(NR, BB), 512, 0, stream>>>(x, Wih, Whh, bih, bhh, out);
    }
}